// Round 6
// baseline (404.398 us; speedup 1.0000x reference)
//
#include <hip/hip_runtime.h>
#include <stdint.h>

// Spiking ConvColumn: temporal PWL-response conv + winner-takes-all.
//   input_spikes [16, 2, 64, 64, 100] fp32 (binary)
//   weight       [32, 2, 3, 3]        fp32 in [0,1]
//   output       [16, 32, 31, 31, 149] fp32 (one-hot spikes)
#define NXS 31
#define NYS 31
#define TP 149
#define TT 100
#define GUARD 47            // low guard (zeros): covers i = t1-n >= -47
#define RSTRIDE 153         // u32/row: 47 guard + 101 entries + 3 pad + 2 spare
#define NROWS 54            // 2 ci * 3 ky * 9 cols (4 sites share 9 cols)
#define LDS_TBL (NROWS * RSTRIDE)   // 8262 u32
#define LDS_MSK (4 * 32 * 6)        // per-site-channel 5-word masks (pad 6)

// Block = 4 waves = sites x0..x0+3. Wave lanes: 0-31 = 32 ch x trains 0-8
// (ci=0), 32-63 = same ch x trains 9-17 (ci=1).
// Table entry k = (C[k]<<16)|M[k]: C = #spikes before time k, M = sum times.
// Row layout [guard zeros | entries 0..100 | pad=total]: a 4-entry read at
// unclamped base min(i,100) yields exactly clamp-semantics values.
__global__ __launch_bounds__(256) void snn_wta(
    const float* __restrict__ in,
    const float* __restrict__ weight,
    float* __restrict__ out)
{
    __shared__ uint32_t lds[LDS_TBL + LDS_MSK];
    uint32_t* tbl  = lds;
    uint32_t* mlds = lds + LDS_TBL;

    const int tid  = threadIdx.x;
    const int wave = tid >> 6;
    const int lane = tid & 63;
    const int half = lane >> 5;
    const int ch   = lane & 31;

    const int bi = blockIdx.x;
    const int xg = bi & 7;                // 8 x-groups of 4 (last has 3)
    const int y  = (bi >> 3) % NYS;
    const int b  = bi / (8 * NYS);
    const int x0 = xg * 4;
    const int x  = x0 + wave;             // this wave's site (x>=31 inactive)

    // zero guards (and everything else; build overwrites entries+pad)
    for (int i = tid; i < LDS_TBL + LDS_MSK; i += 256) lds[i] = 0;

    // per-lane response params: r(tau)=tau/16 for tau<=m=floor(16w);
    // (48w-tau)/32 for m<tau<=n=ceil(48w)-1.
    float wA[9]; int mA[9], nA[9];
    {
        const float* wrow = weight + ch * 18 + half * 9;
#pragma unroll
        for (int j = 0; j < 9; ++j) {
            float w = wrow[j];
            float a48 = 48.0f * w;
            int m = (int)floorf(16.0f * w);
            int n = (int)ceilf(a48) - 1;
            if (n < m) n = m;
            wA[j] = a48; mA[j] = m; nA[j] = n;
        }
    }
    __syncthreads();

    // ---- build 54 rows: row r -> wave r&3, lane r>>2 (parallel across waves)
    {
        const int r = ((lane) << 2) | wave;
        if (r < NROWS) {
            const int ci = r / 27, rem = r % 27;
            const int ky = rem / 9, col = rem % 9;
            const int h = 2 * y + ky, wc = 2 * x0 + col;
            if (wc < 64) {
                const float4* rowp = (const float4*)(in +
                    (size_t)(((b * 2 + ci) * 64 + h) * 64 + wc) * TT);
                uint32_t* t = tbl + r * RSTRIDE + GUARD;   // entry-0 ptr
                int cr = 0, mr = 0, u = 0;
#pragma unroll 5
                for (int chunk = 0; chunk < 25; ++chunk) {
                    float4 v = rowp[chunk];
                    t[u] = (uint32_t)((cr << 16) | mr);
                    if (v.x > 0.5f) { cr++; mr += u; } u++;
                    t[u] = (uint32_t)((cr << 16) | mr);
                    if (v.y > 0.5f) { cr++; mr += u; } u++;
                    t[u] = (uint32_t)((cr << 16) | mr);
                    if (v.z > 0.5f) { cr++; mr += u; } u++;
                    t[u] = (uint32_t)((cr << 16) | mr);
                    if (v.w > 0.5f) { cr++; mr += u; } u++;
                }
                const uint32_t tot = (uint32_t)((cr << 16) | mr);
                t[100] = tot; t[101] = tot; t[102] = tot; t[103] = tot;
            }
        }
    }
    __syncthreads();

    // ---- batch-4 jump-scan WTA ----
    uint32_t m0 = 0, m1 = 0, m2 = 0, m3 = 0, m4 = 0;   // 149-bit spike mask
    if (x < NXS) {
        const uint32_t* TB[9];
#pragma unroll
        for (int j = 0; j < 9; ++j) {
            const int row = half * 27 + (j / 3) * 9 + (2 * wave + j % 3);
            TB[j] = tbl + row * RSTRIDE + GUARD;
        }
        int tp = 1;                         // tp=0: empty window, no spike
        while (tp < TP) {
            const int t1 = tp - 1;
            const int b0 = (tp < TT) ? tp : TT;          // uniform
            uint32_t P0a = 0, P0b = 0, P0c = 0, P0d = 0;
            uint32_t P1a = 0, P1b = 0, P1c = 0, P1d = 0;
            uint32_t P2a = 0, P2b = 0, P2c = 0, P2d = 0;
            float Fa = 0.f, Fb = 0.f, Fc = 0.f, Fd = 0.f;
#pragma unroll
            for (int j = 0; j < 9; ++j) {
                const uint32_t* tj = TB[j];
                int b1 = t1 - mA[j]; b1 = b1 > TT ? TT : b1;  // low: guard=0
                int b2 = t1 - nA[j]; b2 = b2 > TT ? TT : b2;
                uint32_t p0a = tj[b0], p0b = tj[b0+1], p0c = tj[b0+2], p0d = tj[b0+3];
                uint32_t p1a = tj[b1], p1b = tj[b1+1], p1c = tj[b1+2], p1d = tj[b1+3];
                uint32_t p2a = tj[b2], p2b = tj[b2+1], p2c = tj[b2+2], p2d = tj[b2+3];
                P0a += p0a; P0b += p0b; P0c += p0c; P0d += p0d;
                P1a += p1a; P1b += p1b; P1c += p1c; P1d += p1d;
                P2a += p2a; P2b += p2b; P2c += p2c; P2d += p2d;
                Fa += wA[j] * (float)(int)((p1a - p2a) >> 16);
                Fb += wA[j] * (float)(int)((p1b - p2b) >> 16);
                Fc += wA[j] * (float)(int)((p1c - p2c) >> 16);
                Fd += wA[j] * (float)(int)((p1d - p2d) >> 16);
            }
            float pot0, pot1, pot2, pot3;
            {
                uint32_t D1, D2; float ft;
#define FINQ(P0q, P1q, P2q, Fq, q, potq)                                   \
                D1 = P0q - P1q; D2 = P1q - P2q; ft = (float)(t1 + q);      \
                potq = (ft * (float)(D1 >> 16) - (float)(D1 & 0xffffu)) * 0.0625f \
                     + (Fq - ft * (float)(D2 >> 16) + (float)(D2 & 0xffffu)) * 0.03125f; \
                potq += __shfl_xor(potq, 32);
                FINQ(P0a, P1a, P2a, Fa, 0, pot0)
                FINQ(P0b, P1b, P2b, Fb, 1, pot1)
                FINQ(P0c, P1c, P2c, Fc, 2, pot2)
                FINQ(P0d, P1d, P2d, Fd, 3, pot3)
#undef FINQ
            }
            // first firing q (uniform ballots, ascending order = sequential)
            int fired = -1;
            if (__ballot(pot0 > 5.4f)) fired = 0;
            else if (tp + 1 < TP && __ballot(pot1 > 5.4f)) fired = 1;
            else if (tp + 2 < TP && __ballot(pot2 > 5.4f)) fired = 2;
            else if (tp + 3 < TP && __ballot(pot3 > 5.4f)) fired = 3;
            if (fired < 0) { tp += 4; continue; }

            float v = (fired == 0) ? pot0 : (fired == 1) ? pot1
                    : (fired == 2) ? pot2 : pot3;
            int c = ch;                     // argmax, ties -> lowest channel
#pragma unroll
            for (int mk = 16; mk >= 1; mk >>= 1) {
                float vo = __shfl_xor(v, mk);
                int co   = __shfl_xor(c, mk);
                if (vo > v || (vo == v && co < c)) { v = vo; c = co; }
            }
            const int ts = tp + fired;
            if (c == ch) {
                const uint32_t bit = 1u << (ts & 31);
                switch (ts >> 5) {          // uniform scalar branch
                    case 0: m0 |= bit; break;
                    case 1: m1 |= bit; break;
                    case 2: m2 |= bit; break;
                    case 3: m3 |= bit; break;
                    default: m4 |= bit; break;
                }
            }
            tp = ts + 48;                   // dep=47 refractory skip
        }
    }

    // ---- stage masks, then block-cooperative contiguous write ----
    if (x < NXS && lane < 32) {
        uint32_t* mm = mlds + (wave * 32 + ch) * 6;
        mm[0] = m0; mm[1] = m1; mm[2] = m2; mm[3] = m3; mm[4] = m4;
    }
    __syncthreads();

    const int nsite = (NXS - x0) < 4 ? (NXS - x0) : 4;
    const int span = nsite * TP;            // <= 596 contiguous dwords
    for (int c = 0; c < 32; ++c) {
        const size_t base =
            (((size_t)(b * 32 + c) * NXS + y) * NYS + x0) * TP;
        for (int d = tid; d < span; d += 256) {
            const int s = d / TP;
            const int t = d - s * TP;
            const uint32_t m = mlds[(s * 32 + c) * 6 + (t >> 5)];
            out[base + d] = ((m >> (t & 31)) & 1u) ? 1.0f : 0.0f;
        }
    }
}

extern "C" void kernel_launch(void* const* d_in, const int* in_sizes, int n_in,
                              void* d_out, int out_size, void* d_ws, size_t ws_size,
                              hipStream_t stream) {
    const float* in = (const float*)d_in[0];   // input_spikes
    const float* wt = (const float*)d_in[1];   // weight
    float* out = (float*)d_out;

    // grid: 16 b x 31 y x 8 x-groups (last group covers 3 sites)
    hipLaunchKernelGGL(snn_wta, dim3(16 * NYS * 8), dim3(256), 0, stream,
                       in, wt, out);
}

// Round 7
// 396.655 us; speedup vs baseline: 1.0195x; 1.0195x over previous
//
#include <hip/hip_runtime.h>
#include <stdint.h>

// Spiking ConvColumn: temporal PWL-response conv + winner-takes-all.
//   input_spikes [16, 2, 64, 64, 100] fp32 (binary)
//   weight       [32, 2, 3, 3]        fp32 in [0,1]
//   output       [16, 32, 31, 31, 149] fp32 (one-hot spikes)
#define NXS 31
#define NYS 31
#define TP 149
#define TT 100
#define GUARD 48            // low guard (zeros): covers i = t1-n >= -47
#define RSTRIDE 164         // u32/row: 48 guard + 101 entries + 15 spare.
                            // 164 % 32 == 4 -> consecutive rows' b128 writes
                            // land on rotating bank-quads (conflict-free).
#define NROWS 54            // 2 ci * 3 ky * 9 cols (4 sites share 9 cols)
#define LDS_TBL (NROWS * RSTRIDE)   // 8856 u32
#define LDS_MSK (4 * 32 * 6)        // per-(site,ch) 5-word masks (pad to 6)

// Block = 4 waves = sites x0..x0+3 sharing one table set (9 columns).
// Wave lanes: 0-31 = 32 ch x trains 0-8 (ci=0); 32-63 = same ch x 9-17 (ci=1).
// Table entry k = (C[k]<<16)|M[k]: C = #spikes before time k, M = sum times.
// Row layout [48 guard zeros | entries 0..100]: reads at min(t1-m,100) need
// no low clamp (negative index -> guard zero = empty prefix).
__global__ __launch_bounds__(256) void snn_wta(
    const float* __restrict__ in,
    const float* __restrict__ weight,
    float* __restrict__ out)
{
    __shared__ uint32_t lds[LDS_TBL + LDS_MSK];
    uint32_t* tbl  = lds;
    uint32_t* mlds = lds + LDS_TBL;

    const int tid  = threadIdx.x;
    const int wave = tid >> 6;
    const int lane = tid & 63;
    const int half = lane >> 5;
    const int ch   = lane & 31;

    const int bi = blockIdx.x;
    const int xg = bi & 7;                // 8 x-groups of 4 (last has 3)
    const int y  = (bi >> 3) % NYS;
    const int b  = bi / (8 * NYS);
    const int x0 = xg * 4;
    const int x  = x0 + wave;             // this wave's site (x>=31 inactive)

    // per-lane response params: r(tau)=tau/16 for tau<=m=floor(16w);
    // (48w-tau)/32 for m<tau<=n=ceil(48w)-1.
    float wA[9]; int mA[9], nA[9];
    {
        const float* wrow = weight + ch * 18 + half * 9;
#pragma unroll
        for (int j = 0; j < 9; ++j) {
            float w = wrow[j];
            float a48 = 48.0f * w;
            int m = (int)floorf(16.0f * w);
            int n = (int)ceilf(a48) - 1;
            if (n < m) n = m;
            wA[j] = a48; mA[j] = m; nA[j] = n;
        }
    }

    // ---- build 54 rows; row r owned by one lane (waves split the rows).
    // Tree-form prefix: 25-step carry chain (vs 100), b128 entry stores.
    {
        const int r = lane + 14 * wave;    // lanes 0..13 of each wave
        if (lane < 14 && r < NROWS) {
            const int ci = r / 27, rem = r % 27;
            const int ky = rem / 9, col = rem % 9;
            const int h = 2 * y + ky, wc = 2 * x0 + col;
            uint32_t* t = tbl + r * RSTRIDE + GUARD;   // entry-0 pointer
            // zero own guard: 12 x b128 (16B-aligned: GUARD%4==0, RSTRIDE%4==0)
            uint4* g = (uint4*)(t - GUARD);
#pragma unroll
            for (int q = 0; q < 12; ++q) g[q] = make_uint4(0u, 0u, 0u, 0u);
            if (wc < 64) {                 // xg=7,col=8 is OOB and unused
                const float4* rowp = (const float4*)(in +
                    (size_t)(((b * 2 + ci) * 64 + h) * 64 + wc) * TT);
                uint32_t run = 0;
#pragma unroll 5
                for (int chunk = 0; chunk < 25; ++chunk) {
                    float4 v = rowp[chunk];
                    const uint32_t u = chunk * 4;
                    uint32_t i0 = (v.x > 0.5f) ? ((1u << 16) | u)       : 0u;
                    uint32_t i1 = (v.y > 0.5f) ? ((1u << 16) | (u + 1)) : 0u;
                    uint32_t i2 = (v.z > 0.5f) ? ((1u << 16) | (u + 2)) : 0u;
                    uint32_t i3 = (v.w > 0.5f) ? ((1u << 16) | (u + 3)) : 0u;
                    uint32_t s01 = i0 + i1;
                    uint32_t e1 = run + i0;
                    uint32_t e2 = run + s01;
                    uint32_t e3 = e2 + i2;
                    *((uint4*)(t + u)) = make_uint4(run, e1, e2, e3);
                    run = e3 + i3;         // single dependent add per chunk
                }
                t[100] = run;              // total = entry 100
            }
        }
    }
    __syncthreads();

    // ---- scalar jump-scan WTA ----
    uint32_t m0 = 0, m1 = 0, m2 = 0, m3 = 0, m4 = 0;   // 149-bit spike mask
    if (x < NXS) {
        const uint32_t* TB[9];
#pragma unroll
        for (int j = 0; j < 9; ++j) {
            const int row = half * 27 + (j / 3) * 9 + (2 * wave + j % 3);
            TB[j] = tbl + row * RSTRIDE + GUARD;
        }
        int tp = 1;                        // tp=0: empty window, no spike
        while (tp < TP) {
            const int t1 = tp - 1;
            const float ft1 = (float)t1;
            const int b0 = (tp < TT) ? tp : TT;          // uniform per half
            uint32_t P0 = 0, P1 = 0, P2 = 0;
            float F = 0.0f;                // sum_j 48w_j * dc2_j
#pragma unroll
            for (int j = 0; j < 9; ++j) {
                const uint32_t* tj = TB[j];
                int i1 = t1 - mA[j]; i1 = i1 > TT ? TT : i1;  // low: guard
                int i2 = t1 - nA[j]; i2 = i2 > TT ? TT : i2;
                uint32_t p0 = tj[b0];
                uint32_t p1 = tj[i1];
                uint32_t p2 = tj[i2];
                P0 += p0; P1 += p1; P2 += p2;
                F += wA[j] * (float)(int)((p1 - p2) >> 16);
            }
            // packed sums/differences are carry-free: sum C <= 900 < 2^16,
            // sum M <= 9*4950 < 2^16.
            const uint32_t D1 = P0 - P1;   // rising window totals
            const uint32_t D2 = P1 - P2;   // falling window totals
            float pot = (ft1 * (float)(D1 >> 16) - (float)(D1 & 0xffffu)) * 0.0625f
                      + (F - ft1 * (float)(D2 >> 16) + (float)(D2 & 0xffffu)) * 0.03125f;
            pot += __shfl_xor(pot, 32);    // combine the two train halves

            if (__ballot(pot > 5.4f)) {    // any channel spikes this step?
                // argmax over 32 channels; ties -> lowest ch (jnp.argmax)
                float v = pot; int c = ch;
#pragma unroll
                for (int mk = 16; mk >= 1; mk >>= 1) {
                    float vo = __shfl_xor(v, mk);
                    int co   = __shfl_xor(c, mk);
                    if (vo > v || (vo == v && co < c)) { v = vo; c = co; }
                }
                if (c == ch) {
                    const uint32_t bit = 1u << (tp & 31);
                    switch (tp >> 5) {     // wave-uniform branch
                        case 0: m0 |= bit; break;
                        case 1: m1 |= bit; break;
                        case 2: m2 |= bit; break;
                        case 3: m3 |= bit; break;
                        default: m4 |= bit; break;
                    }
                }
                tp += 48;                  // dep=47 refractory skip
            } else {
                tp += 1;
            }
        }
    }

    // ---- stage masks, then block-cooperative contiguous write ----
    if (lane < 32) {                       // inactive wave writes zeros
        uint32_t* mm = mlds + (wave * 32 + ch) * 6;
        mm[0] = m0; mm[1] = m1; mm[2] = m2; mm[3] = m3; mm[4] = m4;
    }
    __syncthreads();

    const int nsite = (NXS - x0) < 4 ? (NXS - x0) : 4;
    const int span = nsite * TP;           // <= 596 contiguous dwords
    for (int c = 0; c < 32; ++c) {
        const size_t base = (((size_t)(b * 32 + c) * NXS + y) * NYS + x0) * TP;
        for (int d = tid; d < span; d += 256) {
            const int s = d / TP;
            const int t = d - s * TP;
            const uint32_t m = mlds[(s * 32 + c) * 6 + (t >> 5)];
            out[base + d] = ((m >> (t & 31)) & 1u) ? 1.0f : 0.0f;
        }
    }
}

extern "C" void kernel_launch(void* const* d_in, const int* in_sizes, int n_in,
                              void* d_out, int out_size, void* d_ws, size_t ws_size,
                              hipStream_t stream) {
    const float* in = (const float*)d_in[0];   // input_spikes
    const float* wt = (const float*)d_in[1];   // weight
    float* out = (float*)d_out;

    // grid: 16 b x 31 y x 8 x-groups (last group covers 3 sites)
    hipLaunchKernelGGL(snn_wta, dim3(16 * NYS * 8), dim3(256), 0, stream,
                       in, wt, out);
}